// Round 2
// baseline (561.204 us; speedup 1.0000x reference)
//
#include <hip/hip_runtime.h>

typedef unsigned short u16;
typedef __bf16 bf16x8 __attribute__((ext_vector_type(8)));
typedef float   f32x4 __attribute__((ext_vector_type(4)));
typedef unsigned short u16x8 __attribute__((ext_vector_type(8)));

// ---------- helpers ----------
__device__ __forceinline__ u16 f2bf(float f) {
    unsigned int u = __builtin_bit_cast(unsigned int, f);
    u = u + 0x7FFFu + ((u >> 16) & 1u);   // round-to-nearest-even
    return (u16)(u >> 16);
}
__device__ __forceinline__ float bf2f(u16 b) {
    return __builtin_bit_cast(float, ((unsigned int)b) << 16);
}
__device__ __forceinline__ void gload16(const void* g, void* l) {
    __builtin_amdgcn_global_load_lds(
        (__attribute__((address_space(1))) void*)g,
        (__attribute__((address_space(3))) void*)l,
        16, 0, 0);
}

#define SB0() __builtin_amdgcn_sched_barrier(0)

// ---------- kernel 1: fp32 -> bf16 cast (h) ----------
__global__ __launch_bounds__(256) void cvt_bf16(const float* __restrict__ x,
                                                u16* __restrict__ y, int n8) {
    int i = blockIdx.x * 256 + threadIdx.x;
    if (i >= n8) return;
    const f32x4* xp = (const f32x4*)x + (size_t)i * 2;
    f32x4 a = xp[0], b = xp[1];
    u16x8 o;
    o[0]=f2bf(a[0]); o[1]=f2bf(a[1]); o[2]=f2bf(a[2]); o[3]=f2bf(a[3]);
    o[4]=f2bf(b[0]); o[5]=f2bf(b[1]); o[6]=f2bf(b[2]); o[7]=f2bf(b[3]);
    ((u16x8*)y)[i] = o;
}

// ---------- kernel 2: Wq [K][N] fp32 -> WqT [N][K] bf16 ----------
__global__ __launch_bounds__(256) void transpose_cvt(const float* __restrict__ W,
                                                     u16* __restrict__ Wt) {
    __shared__ u16 tile[64][65];
    const int c0 = blockIdx.x * 64;
    const int r0 = blockIdx.y * 64;
    const int col = threadIdx.x & 63;
    const int rb  = (threadIdx.x >> 6) * 16;
    #pragma unroll
    for (int rr = 0; rr < 16; ++rr)
        tile[rb + rr][col] = f2bf(W[(size_t)(r0 + rb + rr) * 1024 + c0 + col]);
    __syncthreads();
    const int k = threadIdx.x & 63;
    #pragma unroll
    for (int rr = 0; rr < 16; ++rr) {
        int n = c0 + rb + rr;
        Wt[(size_t)n * 1024 + r0 + k] = tile[k][rb + rr];
    }
}

// ---------- kernel 3: W2T[b][j][h*64+d] = sum_e M0[b,h,d,e]*Wo[h*64+e][j] ----------
// Compute as before (m0s broadcast reads are conflict-free), but stage the
// per-thread results in padded LDS and write with lane=d -> 128 B-contiguous
// stores (old version: 4.2M scattered 2 B stores = ~270 MB effective traffic).
__global__ __launch_bounds__(256) void build_w2t(const float* __restrict__ M0,
                                                 const float* __restrict__ Wo,
                                                 u16* __restrict__ W2T) {
    const int jq = blockIdx.x, h = blockIdx.y, b = blockIdx.z;
    const int tid = threadIdx.x;
    const int j = jq * 256 + tid;
    __shared__ float m0s[64 * 64];
    __shared__ u16 outs[256][66];   // +2 pad: conflict-free stage/read
    const float* m0p = M0 + ((size_t)b * 16 + h) * 4096;
    for (int i = tid; i < 4096; i += 256) m0s[i] = m0p[i];
    __syncthreads();
    float wo[64];
    #pragma unroll
    for (int e = 0; e < 64; ++e) wo[e] = Wo[(size_t)(h * 64 + e) * 1024 + j];
    #pragma unroll 1
    for (int d = 0; d < 64; ++d) {
        float s = 0.f;
        #pragma unroll
        for (int e = 0; e < 64; ++e) s += m0s[d * 64 + e] * wo[e];
        outs[tid][d] = f2bf(s);
    }
    __syncthreads();
    const int d = tid & 63, jr = tid >> 6;
    u16* wp = W2T + (size_t)b * 1024 * 1024 + (size_t)(jq * 256) * 1024 + h * 64 + d;
    #pragma unroll 1
    for (int it = 0; it < 64; ++it) {
        int jl = it * 4 + jr;
        wp[(size_t)jl * 1024] = outs[jl][d];
    }
}

// ---------- GEMM: 256x256 tile, BK=64, pipelined 8-phase (T2+T3+T4+T5) ----------
// C[M,N] = A[M,K] * Bt[N,K]^T, bf16 in, fp32 acc.
// 8 waves (2M x 4N), 512 threads, 128 KiB LDS, slots as before.
// NEW vs prev round: register-fragment loads are pipelined ONE PHASE AHEAD of
// their consuming MFMA quad (same registers, no extra VGPR):
//   quad order  p0: a0*b01   p1: a0*b23   p2: a1*b01   p3: a1*b23
//   reads       p0-top: b23(T)        p1-bottom: a1(T)  [after a0's last use]
//               p3-top: b01(T+1)      p3-bottom: a0(T+1) [after a1's last use]
//   lgkm waits  p0: lgkmcnt(4)  p1: lgkmcnt(0)  p2: lgkmcnt(0)  p3: none
// so every lgkm wait covers reads issued >= one MFMA cluster earlier -> LDS
// service overlaps the matrix pipe instead of serializing with it.
// Staging: one half-tile per phase, (T+2).{A0,B0,B1,A1} at p0..p3; single
// s_waitcnt vmcnt(6) per K-tile at p2 (8 ops of (T+1) + 3 stages issued ->
// complete 8, leave 6) publishes tile T+1 before its first reg-read at p3.
// All slot WAR hazards checked against the barrier schedule (see per-phase
// comments). Tail: tile NT-2 uses vmcnt(0); guards skip stages/next-reads.

#define STAGE(GB, SLOT) \
    gload16((GB) + g0, (char*)(SLOT) + d0); \
    gload16((GB) + g1, (char*)(SLOT) + d1);

#define READ_AR(SLOT) \
    _Pragma("unroll") for (int f = 0; f < 4; ++f) \
    _Pragma("unroll") for (int kk = 0; kk < 2; ++kk) \
        ar[f][kk] = *(const bf16x8*)((const char*)(SLOT) + \
            (((rhA + f * 32) << 7) + (cA ^ (kk << 6))));

#define READ_BX(ARR, SLOT) \
    _Pragma("unroll") for (int g = 0; g < 2; ++g) \
    _Pragma("unroll") for (int kk = 0; kk < 2; ++kk) \
        ARR[g][kk] = *(const bf16x8*)((const char*)(SLOT) + \
            (((rhB + g * 64) << 7) + (cB ^ (kk << 6))));

#define MFMA_Q(FB, GB, BARR) \
    __builtin_amdgcn_s_setprio(1); \
    _Pragma("unroll") for (int f = 0; f < 4; ++f) \
    _Pragma("unroll") for (int g = 0; g < 2; ++g) \
    _Pragma("unroll") for (int kk = 0; kk < 2; ++kk) \
        acc[(FB)+f][(GB)+g] = __builtin_amdgcn_mfma_f32_16x16x32_bf16( \
            ar[f][kk], BARR[g][kk], acc[(FB)+f][(GB)+g], 0, 0, 0); \
    __builtin_amdgcn_s_setprio(0);

#define TILE_BODY(T, BB, VMW) { \
    /* p0: Q(a0*b01). top: read b23(T) (lead-1 for p1). bottom: stage (T+2).A0 */ \
    /* into [BB][0] - a0(T) reads (T-1 p3-bottom) completed by this phase's   */ \
    /* lgkm(4) + MFMA duration covers wave skew before the stage write lands. */ \
    READ_BX(b23r, lds[BB][3]); \
    SB0(); \
    __builtin_amdgcn_s_barrier(); \
    asm volatile("s_waitcnt lgkmcnt(4)" ::: "memory"); \
    SB0(); \
    MFMA_Q(0, 0, b01r); \
    if ((T) + 2 < NT) { STAGE(A0p + ((T) + 2) * 64, lds[BB][0]); } \
    SB0(); \
    __builtin_amdgcn_s_barrier(); \
    /* p1: Q(a0*b23). stage (T+2).B0 (b01(T) reads done at p0's lgkm). */ \
    /* bottom: read a1(T) into ar - after a0's last use (reg WAR ok).  */ \
    if ((T) + 2 < NT) { STAGE(B0p + ((T) + 2) * 64, lds[BB][2]); } \
    SB0(); \
    __builtin_amdgcn_s_barrier(); \
    asm volatile("s_waitcnt lgkmcnt(0)" ::: "memory"); \
    SB0(); \
    MFMA_Q(0, 2, b23r); \
    READ_AR(lds[BB][1]); \
    SB0(); \
    __builtin_amdgcn_s_barrier(); \
    /* p2: Q(a1*b01). stage (T+2).B1 (b23(T) reads done at p1's lgkm). */ \
    /* vmcnt: publish ALL of tile T+1 before its first reg-read at p3. */ \
    if ((T) + 2 < NT) { STAGE(B1p + ((T) + 2) * 64, lds[BB][3]); } \
    asm volatile(VMW ::: "memory"); \
    SB0(); \
    __builtin_amdgcn_s_barrier(); \
    asm volatile("s_waitcnt lgkmcnt(0)" ::: "memory"); \
    SB0(); \
    MFMA_Q(4, 0, b01r); \
    SB0(); \
    __builtin_amdgcn_s_barrier(); \
    /* p3: Q(a1*b23). top: read b01(T+1) (b01 dead after p2), stage (T+2).A1 */ \
    /* (a1(T) reads done at p2's lgkm). bottom: read a0(T+1) after a1's last */ \
    /* use; completed by next tile's p0 lgkm(4).                             */ \
    if ((T) + 1 < NT) { READ_BX(b01r, lds[(BB)^1][2]); } \
    if ((T) + 2 < NT) { STAGE(A1p + ((T) + 2) * 64, lds[BB][1]); } \
    SB0(); \
    __builtin_amdgcn_s_barrier(); \
    MFMA_Q(4, 2, b23r); \
    if ((T) + 1 < NT) { READ_AR(lds[(BB)^1][0]); } \
    SB0(); \
    __builtin_amdgcn_s_barrier(); \
}

template <int ACC_SSQ, int HAS_SCALE, typename CT>
__global__ __launch_bounds__(512) void gemm256_8ph(const u16* __restrict__ A,
                                                   const u16* __restrict__ Bt,
                                                   CT* __restrict__ C,
                                                   float* __restrict__ ssq,
                                                   int M, int N, int K,
                                                   long long bt_batch_stride,
                                                   int rpb_log2) {
    __shared__ u16 lds[2][4][8192];   // 128 KiB
    const int tid  = threadIdx.x;
    const int lane = tid & 63;
    const int w    = tid >> 6;
    const int wm   = w >> 2;          // 0..1
    const int wn   = w & 3;           // 0..3

    // XCD-aware swizzle: 4 n-tiles of an m-tile share one XCD's L2.
    const int id  = blockIdx.x;
    const int xcd = id & 7;
    const int loc = id >> 3;
    const int mpx = (M >> 8) >> 3;            // m-tiles per XCD (16)
    const int mt  = xcd * mpx + (loc >> 2);
    const int ntt = loc & 3;
    const int m0  = mt << 8;
    const int n0  = ntt << 8;

    const u16* Btb = Bt + (size_t)(m0 >> rpb_log2) * (size_t)bt_batch_stride;
    const u16* A0p = A   + (size_t)m0 * K;
    const u16* A1p = A0p + (size_t)128 * K;
    const u16* B0p = Btb + (size_t)n0 * K;
    const u16* B1p = B0p + (size_t)128 * K;

    // staging: thread t loads rows (t>>3) and 64+(t>>3); source chunk
    // pre-swizzled so linear LDS + swizzled read is consistent (involution).
    const int    trow   = tid >> 3;
    const int    tchunk = (tid & 7) ^ (trow & 7);
    const size_t g0 = (size_t)trow * K + (size_t)tchunk * 8;   // u16 elems
    const size_t g1 = g0 + (size_t)64 * K;
    const int    d0 = tid * 16;                                 // bytes
    const int    d1 = d0 + 8192;

    const int NT = K >> 6;    // K-tiles (16); NT even, NT >= 4 assumed

    // per-lane LDS read bases (swizzle XOR constant per lane)
    const int rm  = lane & 15;
    const int kqb = (lane >> 4) << 4;                // byte offset of kq
    const int rhA = wm * 16 + rm;
    const int cA  = kqb ^ ((rhA & 7) << 4);
    const int rhB = wn * 16 + rm;
    const int cB  = kqb ^ ((rhB & 7) << 4);

    bf16x8 ar[4][2], b01r[2][2], b23r[2][2];
    f32x4 acc[8][4] = {};

    // ---- prologue: stage T0+T1 fully; vmcnt(8) -> T0 landed; read a0,b01(T0)
    STAGE(A0p + 0,  lds[0][0]);
    STAGE(B0p + 0,  lds[0][2]);
    STAGE(B1p + 0,  lds[0][3]);
    STAGE(A1p + 0,  lds[0][1]);
    STAGE(A0p + 64, lds[1][0]);
    STAGE(B0p + 64, lds[1][2]);
    STAGE(B1p + 64, lds[1][3]);
    STAGE(A1p + 64, lds[1][1]);
    asm volatile("s_waitcnt vmcnt(8)" ::: "memory");
    __builtin_amdgcn_s_barrier();
    READ_BX(b01r, lds[0][2]);
    READ_AR(lds[0][0]);
    SB0();

    #pragma unroll 1
    for (int T = 0; T < NT - 2; T += 2) {
        TILE_BODY(T, 0, "s_waitcnt vmcnt(6)");
        TILE_BODY(T + 1, 1, "s_waitcnt vmcnt(6)");
    }
    TILE_BODY(NT - 2, 0, "s_waitcnt vmcnt(0)");
    TILE_BODY(NT - 1, 1, "s_waitcnt vmcnt(0)");

    // ---- epilogue ----  C/D: col=lane&15, row=(lane>>4)*4+reg [m89]
    __syncthreads();
    float* lred = (float*)&lds[0][0][0];   // 256 floats, LDS reuse
    if constexpr (HAS_SCALE) {
        if (tid < 256) {
            float q = ssq[m0 + tid];
            lred[tid] = 1.0f / fmaxf(sqrtf(q), 1e-12f);
        }
        __syncthreads();
    }
    if constexpr (ACC_SSQ) {
        if (tid < 256) lred[tid] = 0.f;
        __syncthreads();
    }
    const int cn = lane & 15;
    const int rq = (lane >> 4) * 4;
    #pragma unroll
    for (int f = 0; f < 8; ++f) {
        const int rbase = f * 32 + wm * 16 + rq;
        #pragma unroll
        for (int r = 0; r < 4; ++r) {
            const size_t rowoff = (size_t)(m0 + rbase + r) * N;
            float s = 0.f;
            #pragma unroll
            for (int g = 0; g < 4; ++g) {
                float x = acc[f][g][r];
                if constexpr (HAS_SCALE) x *= lred[rbase + r];
                if constexpr (ACC_SSQ) s += x * x;
                const int col = n0 + g * 64 + wn * 16 + cn;
                if constexpr (sizeof(CT) == 2) ((u16*)C)[rowoff + col] = f2bf(x);
                else                           C[rowoff + col] = x;
            }
            if constexpr (ACC_SSQ) {
                s += __shfl_xor(s, 1);
                s += __shfl_xor(s, 2);
                s += __shfl_xor(s, 4);
                s += __shfl_xor(s, 8);
                if (cn == 0) atomicAdd(&lred[rbase + r], s);  // 4 wn-waves/row
            }
        }
    }
    if constexpr (ACC_SSQ) {
        __syncthreads();
        if (tid < 256) atomicAdd(&ssq[m0 + tid], lred[tid]);  // 4 n-blocks/row
    }
}

// ---------- launch ----------
// B=4, S=8192, HID=PROJ=1024, NH=16, HD=64; M = B*S = 32768
// ws usage: 77.7 MiB. hbf lives in d_out's first half (dead after gemm1;
// gemm2 overwrites all of d_out — stream-ordered, safe).
extern "C" void kernel_launch(void* const* d_in, const int* in_sizes, int n_in,
                              void* d_out, int out_size, void* d_ws, size_t ws_size,
                              hipStream_t stream) {
    const float* h  = (const float*)d_in[0];   // [4,8192,1024]
    const float* Wq = (const float*)d_in[1];   // [1024,1024]
    const float* Wo = (const float*)d_in[7];   // [1024,1024]
    const float* M0 = (const float*)d_in[8];   // [4,16,64,64]
    float* out = (float*)d_out;

    char* ws = (char*)d_ws;
    u16*   hbf  = (u16*)d_out;                 // 67,108,864 B (first half of out)
    u16*   P    = (u16*)(ws);                  // 67,108,864 B
    u16*   WqT  = (u16*)(ws + 67108864);       //  2,097,152 B
    u16*   W2T  = (u16*)(ws + 69206016);       //  8,388,608 B
    float* ssq  = (float*)(ws + 77594624);     //    131,072 B  (end: 77,725,696)

    const int M = 32768, N = 1024, K = 1024;

    hipMemsetAsync(ssq, 0, M * sizeof(float), stream);   // graph-capture-safe
    cvt_bf16<<<16384, 256, 0, stream>>>(h, hbf, (M * K) / 8);
    transpose_cvt<<<dim3(16, 16), 256, 0, stream>>>(Wq, WqT);
    build_w2t<<<dim3(4, 16, 4), 256, 0, stream>>>(M0, Wo, W2T);
    // P = h @ Wq (bf16, un-normalized) + per-row ssq via atomics
    gemm256_8ph<1, 0, u16><<<512, 512, 0, stream>>>(
        hbf, WqT, P, ssq, M, N, K, 0, 0);
    // out = (1/max(sqrt(ssq),1e-12))[m] * (P @ W2T[batch]) ; batch = m >> 13
    gemm256_8ph<0, 1, float><<<512, 512, 0, stream>>>(
        P, W2T, out, ssq, M, N, K, (long long)1024 * 1024, 13);
}

// Round 3
// 398.894 us; speedup vs baseline: 1.4069x; 1.4069x over previous
//
#include <hip/hip_runtime.h>

typedef unsigned short u16;
typedef __bf16 bf16x8 __attribute__((ext_vector_type(8)));
typedef float   f32x4 __attribute__((ext_vector_type(4)));
typedef unsigned short u16x8 __attribute__((ext_vector_type(8)));

// ---------- helpers ----------
__device__ __forceinline__ u16 f2bf(float f) {
    unsigned int u = __builtin_bit_cast(unsigned int, f);
    u = u + 0x7FFFu + ((u >> 16) & 1u);   // round-to-nearest-even
    return (u16)(u >> 16);
}
__device__ __forceinline__ float bf2f(u16 b) {
    return __builtin_bit_cast(float, ((unsigned int)b) << 16);
}
__device__ __forceinline__ void gload16(const void* g, void* l) {
    __builtin_amdgcn_global_load_lds(
        (__attribute__((address_space(1))) void*)g,
        (__attribute__((address_space(3))) void*)l,
        16, 0, 0);
}

#define S_BARRIER() asm volatile("s_barrier" ::: "memory")

// ---------- kernel 1: fp32 -> bf16 cast (h) ----------
__global__ __launch_bounds__(256) void cvt_bf16(const float* __restrict__ x,
                                                u16* __restrict__ y, int n8) {
    int i = blockIdx.x * 256 + threadIdx.x;
    if (i >= n8) return;
    const f32x4* xp = (const f32x4*)x + (size_t)i * 2;
    f32x4 a = xp[0], b = xp[1];
    u16x8 o;
    o[0]=f2bf(a[0]); o[1]=f2bf(a[1]); o[2]=f2bf(a[2]); o[3]=f2bf(a[3]);
    o[4]=f2bf(b[0]); o[5]=f2bf(b[1]); o[6]=f2bf(b[2]); o[7]=f2bf(b[3]);
    ((u16x8*)y)[i] = o;
}

// ---------- kernel 2: Wq [K][N] fp32 -> WqT [N][K] bf16 ----------
__global__ __launch_bounds__(256) void transpose_cvt(const float* __restrict__ W,
                                                     u16* __restrict__ Wt) {
    __shared__ u16 tile[64][65];
    const int c0 = blockIdx.x * 64;
    const int r0 = blockIdx.y * 64;
    const int col = threadIdx.x & 63;
    const int rb  = (threadIdx.x >> 6) * 16;
    #pragma unroll
    for (int rr = 0; rr < 16; ++rr)
        tile[rb + rr][col] = f2bf(W[(size_t)(r0 + rb + rr) * 1024 + c0 + col]);
    __syncthreads();
    const int k = threadIdx.x & 63;
    #pragma unroll
    for (int rr = 0; rr < 16; ++rr) {
        int n = c0 + rb + rr;
        Wt[(size_t)n * 1024 + r0 + k] = tile[k][rb + rr];
    }
}

// ---------- kernel 3: W2T[b][j][h*64+d] = sum_e M0[b,h,d,e]*Wo[h*64+e][j] ----------
// Results staged in padded LDS, then written with lane=d -> 128 B-contiguous
// stores (vs 4.2M scattered 2 B stores in the original).
__global__ __launch_bounds__(256) void build_w2t(const float* __restrict__ M0,
                                                 const float* __restrict__ Wo,
                                                 u16* __restrict__ W2T) {
    const int jq = blockIdx.x, h = blockIdx.y, b = blockIdx.z;
    const int tid = threadIdx.x;
    const int j = jq * 256 + tid;
    __shared__ float m0s[64 * 64];
    __shared__ u16 outs[256][66];   // +2 pad: conflict-free stage/read
    const float* m0p = M0 + ((size_t)b * 16 + h) * 4096;
    for (int i = tid; i < 4096; i += 256) m0s[i] = m0p[i];
    __syncthreads();
    float wo[64];
    #pragma unroll
    for (int e = 0; e < 64; ++e) wo[e] = Wo[(size_t)(h * 64 + e) * 1024 + j];
    #pragma unroll 1
    for (int d = 0; d < 64; ++d) {
        float s = 0.f;
        #pragma unroll
        for (int e = 0; e < 64; ++e) s += m0s[d * 64 + e] * wo[e];
        outs[tid][d] = f2bf(s);
    }
    __syncthreads();
    const int d = tid & 63, jr = tid >> 6;
    u16* wp = W2T + (size_t)b * 1024 * 1024 + (size_t)(jq * 256) * 1024 + h * 64 + d;
    #pragma unroll 1
    for (int it = 0; it < 64; ++it) {
        int jl = it * 4 + jr;
        wp[(size_t)jl * 1024] = outs[jl][d];
    }
}

// ---------- GEMM: 256x256 tile, BK=64, 8-phase (T2+T3+T4+T5) ----------
// C[M,N] = A[M,K] * Bt[N,K]^T, bf16 in, fp32 acc.
// Round-1 verified body (848 TF @ K=1024) with two audited deltas:
//  (a) mid-phase barriers removed (8 -> 4 barriers/K-tile). WAR audit: every
//      STAGE targets a slot whose readers completed before the preceding
//      end-of-phase barrier (each wave's ds_reads complete before its own
//      MFMA wait, which precedes that barrier; stage is issued after it).
//      Publish correctness rests on the per-K-tile counted vmcnt + barrier,
//      unchanged. Also lets the compiler interleave ds_reads into the MFMA
//      cluster (round-2 showed pinning these apart serializes the pipes).
//  (b) tail fix: last two K-tiles use vmcnt(0) — round-1's vmcnt(6) at
//      NT-2.p3 only proves A0(NT-1) landed, not B0/B1/A1 (latent race).
// Stage schedule per tile T: p0:(T+1).A1  p1:(T+2).A0  p2:(T+2).B0
// p3:(T+2).B1 + vmcnt(6) (retires all of tile T+1; 6 = 3 half-tiles left).
// LDS swizzle (both-sides, rule #21): linear dest for global_load_lds, global
// SOURCE chunk pre-permuted chunk^=row&7, reads XOR byte^=((row&7)<<4).
// Grid 512 = 128 m-tiles x 4 n-tiles; xcd=id&7, all 4 n-tiles of an m-tile
// on one XCD (A panel L2-resident; 512%8==0 bijective).

#define STAGE(GB, SLOT) \
    gload16((GB) + g0, (char*)(SLOT) + d0); \
    gload16((GB) + g1, (char*)(SLOT) + d1);

#define READ_A(SLOT) \
    _Pragma("unroll") for (int f = 0; f < 4; ++f) \
    _Pragma("unroll") for (int kk = 0; kk < 2; ++kk) \
        a[f][kk] = *(const bf16x8*)((const char*)(SLOT) + \
            (((rhA + f * 32) << 7) + (cA ^ (kk << 6))));

#define READ_B(SLOT, GB) \
    _Pragma("unroll") for (int g = 0; g < 2; ++g) \
    _Pragma("unroll") for (int kk = 0; kk < 2; ++kk) \
        b[(GB) + g][kk] = *(const bf16x8*)((const char*)(SLOT) + \
            (((rhB + g * 64) << 7) + (cB ^ (kk << 6))));

#define MFMA_QUAD(FB, GB) \
    __builtin_amdgcn_s_setprio(1); \
    _Pragma("unroll") for (int f = 0; f < 4; ++f) \
    _Pragma("unroll") for (int g = 0; g < 2; ++g) \
    _Pragma("unroll") for (int kk = 0; kk < 2; ++kk) \
        acc[(FB) + f][(GB) + g] = __builtin_amdgcn_mfma_f32_16x16x32_bf16( \
            a[f][kk], b[(GB) + g][kk], acc[(FB) + f][(GB) + g], 0, 0, 0); \
    __builtin_amdgcn_s_setprio(0);

#define TILE_BODY(T, BB, VMW) { \
    bf16x8 a[4][2], b[4][2]; \
    /* p0: reads a0,b01(T); stage (T+1).A1 (slot's old a1(T-1) read done   */ \
    /* before T-1.p2's barrier).                                           */ \
    READ_A(lds[BB][0]); \
    READ_B(lds[BB][2], 0); \
    if ((T) + 1 < NT) { STAGE(A1p + ((T) + 1) * 64, lds[(BB) ^ 1][1]); } \
    MFMA_QUAD(0, 0); \
    S_BARRIER(); \
    /* p1: reads b23(T); stage (T+2).A0 over a0(T) (reads done < p0 bar). */ \
    READ_B(lds[BB][3], 2); \
    if ((T) + 2 < NT) { STAGE(A0p + ((T) + 2) * 64, lds[BB][0]); } \
    MFMA_QUAD(0, 2); \
    S_BARRIER(); \
    /* p2: reads a1(T); stage (T+2).B0 over b01(T) (reads done < p0 bar). */ \
    READ_A(lds[BB][1]); \
    if ((T) + 2 < NT) { STAGE(B0p + ((T) + 2) * 64, lds[BB][2]); } \
    MFMA_QUAD(4, 0); \
    S_BARRIER(); \
    /* p3: stage (T+2).B1 over b23(T) (reads done < p1 bar); counted vmcnt */ \
    /* publishes tile T+1 for next p0.                                     */ \
    if ((T) + 2 < NT) { STAGE(B1p + ((T) + 2) * 64, lds[BB][3]); } \
    MFMA_QUAD(4, 2); \
    asm volatile(VMW ::: "memory"); \
    S_BARRIER(); \
}

template <int ACC_SSQ, int HAS_SCALE, typename CT>
__global__ __launch_bounds__(512) void gemm256_8ph(const u16* __restrict__ A,
                                                   const u16* __restrict__ Bt,
                                                   CT* __restrict__ C,
                                                   float* __restrict__ ssq,
                                                   int M, int N, int K,
                                                   long long bt_batch_stride,
                                                   int rpb_log2) {
    __shared__ u16 lds[2][4][8192];   // 128 KiB
    const int tid  = threadIdx.x;
    const int lane = tid & 63;
    const int w    = tid >> 6;
    const int wm   = w >> 2;          // 0..1
    const int wn   = w & 3;           // 0..3

    // XCD-aware swizzle: 4 n-tiles of an m-tile share one XCD's L2.
    const int id  = blockIdx.x;
    const int xcd = id & 7;
    const int loc = id >> 3;
    const int mpx = (M >> 8) >> 3;            // m-tiles per XCD (16)
    const int mt  = xcd * mpx + (loc >> 2);
    const int ntt = loc & 3;
    const int m0  = mt << 8;
    const int n0  = ntt << 8;

    const u16* Btb = Bt + (size_t)(m0 >> rpb_log2) * (size_t)bt_batch_stride;
    const u16* A0p = A   + (size_t)m0 * K;
    const u16* A1p = A0p + (size_t)128 * K;
    const u16* B0p = Btb + (size_t)n0 * K;
    const u16* B1p = B0p + (size_t)128 * K;

    // staging: thread t loads rows (t>>3) and 64+(t>>3); source chunk
    // pre-swizzled so linear LDS + swizzled read is consistent (involution).
    const int    trow   = tid >> 3;
    const int    tchunk = (tid & 7) ^ (trow & 7);
    const size_t g0 = (size_t)trow * K + (size_t)tchunk * 8;   // u16 elems
    const size_t g1 = g0 + (size_t)64 * K;
    const int    d0 = tid * 16;                                 // bytes
    const int    d1 = d0 + 8192;

    const int NT = K >> 6;    // K-tiles (16); NT even, NT >= 4 assumed

    // per-lane LDS read bases (swizzle XOR constant per lane)
    const int rm  = lane & 15;
    const int kqb = (lane >> 4) << 4;                // byte offset of kq
    const int rhA = wm * 16 + rm;
    const int cA  = kqb ^ ((rhA & 7) << 4);
    const int rhB = wn * 16 + rm;
    const int cB  = kqb ^ ((rhB & 7) << 4);

    f32x4 acc[8][4] = {};

    // ---- prologue: stage T0 fully + T1.{A0,B0,B1}; vmcnt(6) -> T0 landed ----
    STAGE(A0p + 0,  lds[0][0]);
    STAGE(B0p + 0,  lds[0][2]);
    STAGE(B1p + 0,  lds[0][3]);
    STAGE(A1p + 0,  lds[0][1]);
    STAGE(A0p + 64, lds[1][0]);
    STAGE(B0p + 64, lds[1][2]);
    STAGE(B1p + 64, lds[1][3]);
    asm volatile("s_waitcnt vmcnt(6)" ::: "memory");
    S_BARRIER();

    #pragma unroll 1
    for (int T = 0; T < NT - 2; T += 2) {
        TILE_BODY(T, 0, "s_waitcnt vmcnt(6)");
        TILE_BODY(T + 1, 1, "s_waitcnt vmcnt(6)");
    }
    // tail: vmcnt(6) at NT-2.p3 would only prove A0(NT-1) landed; drain fully.
    TILE_BODY(NT - 2, 0, "s_waitcnt vmcnt(0)");
    TILE_BODY(NT - 1, 1, "s_waitcnt vmcnt(0)");

    // ---- epilogue ----  C/D: col=lane&15, row=(lane>>4)*4+reg [m89]
    __syncthreads();
    float* lred = (float*)&lds[0][0][0];   // 256 floats, LDS reuse
    if constexpr (HAS_SCALE) {
        if (tid < 256) {
            float q = ssq[m0 + tid];
            lred[tid] = 1.0f / fmaxf(sqrtf(q), 1e-12f);
        }
        __syncthreads();
    }
    if constexpr (ACC_SSQ) {
        if (tid < 256) lred[tid] = 0.f;
        __syncthreads();
    }
    const int cn = lane & 15;
    const int rq = (lane >> 4) * 4;
    #pragma unroll
    for (int f = 0; f < 8; ++f) {
        const int rbase = f * 32 + wm * 16 + rq;
        #pragma unroll
        for (int r = 0; r < 4; ++r) {
            const size_t rowoff = (size_t)(m0 + rbase + r) * N;
            float s = 0.f;
            #pragma unroll
            for (int g = 0; g < 4; ++g) {
                float x = acc[f][g][r];
                if constexpr (HAS_SCALE) x *= lred[rbase + r];
                if constexpr (ACC_SSQ) s += x * x;
                const int col = n0 + g * 64 + wn * 16 + cn;
                if constexpr (sizeof(CT) == 2) ((u16*)C)[rowoff + col] = f2bf(x);
                else                           C[rowoff + col] = x;
            }
            if constexpr (ACC_SSQ) {
                s += __shfl_xor(s, 1);
                s += __shfl_xor(s, 2);
                s += __shfl_xor(s, 4);
                s += __shfl_xor(s, 8);
                if (cn == 0) atomicAdd(&lred[rbase + r], s);  // 4 wn-waves/row
            }
        }
    }
    if constexpr (ACC_SSQ) {
        __syncthreads();
        if (tid < 256) atomicAdd(&ssq[m0 + tid], lred[tid]);  // 4 n-blocks/row
    }
}

// ---------- launch ----------
// B=4, S=8192, HID=PROJ=1024, NH=16, HD=64; M = B*S = 32768
// ws usage: 77.7 MiB. hbf lives in d_out's first half (dead after gemm1;
// gemm2 overwrites all of d_out — stream-ordered, safe).
extern "C" void kernel_launch(void* const* d_in, const int* in_sizes, int n_in,
                              void* d_out, int out_size, void* d_ws, size_t ws_size,
                              hipStream_t stream) {
    const float* h  = (const float*)d_in[0];   // [4,8192,1024]
    const float* Wq = (const float*)d_in[1];   // [1024,1024]
    const float* Wo = (const float*)d_in[7];   // [1024,1024]
    const float* M0 = (const float*)d_in[8];   // [4,16,64,64]
    float* out = (float*)d_out;

    char* ws = (char*)d_ws;
    u16*   hbf  = (u16*)d_out;                 // 67,108,864 B (first half of out)
    u16*   P    = (u16*)(ws);                  // 67,108,864 B
    u16*   WqT  = (u16*)(ws + 67108864);       //  2,097,152 B
    u16*   W2T  = (u16*)(ws + 69206016);       //  8,388,608 B
    float* ssq  = (float*)(ws + 77594624);     //    131,072 B  (end: 77,725,696)

    const int M = 32768, N = 1024, K = 1024;

    hipMemsetAsync(ssq, 0, M * sizeof(float), stream);   // graph-capture-safe
    cvt_bf16<<<16384, 256, 0, stream>>>(h, hbf, (M * K) / 8);
    transpose_cvt<<<dim3(16, 16), 256, 0, stream>>>(Wq, WqT);
    build_w2t<<<dim3(4, 16, 4), 256, 0, stream>>>(M0, Wo, W2T);
    // P = h @ Wq (bf16, un-normalized) + per-row ssq via atomics
    gemm256_8ph<1, 0, u16><<<512, 512, 0, stream>>>(
        hbf, WqT, P, ssq, M, N, K, 0, 0);
    // out = (1/max(sqrt(ssq),1e-12))[m] * (P @ W2T[batch]) ; batch = m >> 13
    gemm256_8ph<0, 1, float><<<512, 512, 0, stream>>>(
        P, W2T, out, ssq, M, N, K, (long long)1024 * 1024, 13);
}

// Round 4
// 375.761 us; speedup vs baseline: 1.4935x; 1.0616x over previous
//
#include <hip/hip_runtime.h>

typedef unsigned short u16;
typedef __bf16 bf16x8 __attribute__((ext_vector_type(8)));
typedef float   f32x4 __attribute__((ext_vector_type(4)));
typedef unsigned short u16x8 __attribute__((ext_vector_type(8)));

// ---------- helpers ----------
__device__ __forceinline__ u16 f2bf(float f) {
    unsigned int u = __builtin_bit_cast(unsigned int, f);
    u = u + 0x7FFFu + ((u >> 16) & 1u);   // round-to-nearest-even
    return (u16)(u >> 16);
}
__device__ __forceinline__ float bf2f(u16 b) {
    return __builtin_bit_cast(float, ((unsigned int)b) << 16);
}
__device__ __forceinline__ void gload16(const void* g, void* l) {
    __builtin_amdgcn_global_load_lds(
        (__attribute__((address_space(1))) void*)g,
        (__attribute__((address_space(3))) void*)l,
        16, 0, 0);
}

#define S_BARRIER() asm volatile("s_barrier" ::: "memory")

// ---------- fused prep: w2t | transpose | ssq-zero | cvt in ONE dispatch ----
// Round-3 showed the 4 prep dispatches serialize (~45 us + gaps) while being
// mutually independent. One grid: blocks [0,256) build W2T, [256,512)
// transpose Wq, [512,544) zero ssq, [544,16928) cast h->bf16. Small jobs at
// low indices dispatch first and hide entirely under the 32-us cvt stream.
// LDS: 50176-B union (w2t: m0s 16K + outs 33.8K; transpose: 8.3K tile) ->
// 3 blocks/CU, 12 waves/CU — enough in-flight loads for cvt to hold HBM BW.
__global__ __launch_bounds__(256) void prep(const float* __restrict__ h,
                                            u16* __restrict__ hbf,
                                            const float* __restrict__ Wq,
                                            u16* __restrict__ WqT,
                                            const float* __restrict__ M0,
                                            const float* __restrict__ Wo,
                                            u16* __restrict__ W2T,
                                            float* __restrict__ ssq) {
    __shared__ __align__(16) char smem[50176];
    const int bid = blockIdx.x;
    const int tid = threadIdx.x;

    if (bid < 256) {
        // ---- build_w2t: W2T[b][j][h*64+d] = sum_e M0[b,h,d,e]*Wo[h*64+e][j]
        // (round-3 verified body; results staged in padded LDS, written with
        //  lane=d -> 128 B-contiguous stores)
        float* m0s = (float*)smem;
        u16 (*outs)[66] = (u16 (*)[66])(smem + 16384);
        const int jq = bid & 3, hh = (bid >> 2) & 15, b = bid >> 6;
        const int j = jq * 256 + tid;
        const float* m0p = M0 + ((size_t)b * 16 + hh) * 4096;
        for (int i = tid; i < 4096; i += 256) m0s[i] = m0p[i];
        __syncthreads();
        float wo[64];
        #pragma unroll
        for (int e = 0; e < 64; ++e) wo[e] = Wo[(size_t)(hh * 64 + e) * 1024 + j];
        #pragma unroll 1
        for (int d = 0; d < 64; ++d) {
            float s = 0.f;
            #pragma unroll
            for (int e = 0; e < 64; ++e) s += m0s[d * 64 + e] * wo[e];
            outs[tid][d] = f2bf(s);
        }
        __syncthreads();
        const int d = tid & 63, jr = tid >> 6;
        u16* wp = W2T + (size_t)b * 1024 * 1024 + (size_t)(jq * 256) * 1024 + hh * 64 + d;
        #pragma unroll 1
        for (int it = 0; it < 64; ++it) {
            int jl = it * 4 + jr;
            wp[(size_t)jl * 1024] = outs[jl][d];
        }
    } else if (bid < 512) {
        // ---- transpose_cvt: Wq [K][N] fp32 -> WqT [N][K] bf16 ----
        u16 (*tile)[65] = (u16 (*)[65])smem;
        const int bb = bid - 256;
        const int c0 = (bb & 15) * 64;
        const int r0 = (bb >> 4) * 64;
        const int col = tid & 63;
        const int rb  = (tid >> 6) * 16;
        #pragma unroll
        for (int rr = 0; rr < 16; ++rr)
            tile[rb + rr][col] = f2bf(Wq[(size_t)(r0 + rb + rr) * 1024 + c0 + col]);
        __syncthreads();
        const int k = tid & 63;
        #pragma unroll
        for (int rr = 0; rr < 16; ++rr) {
            int n = c0 + rb + rr;
            WqT[(size_t)n * 1024 + r0 + k] = tile[k][rb + rr];
        }
    } else if (bid < 544) {
        // ---- ssq zero: 32768 floats across 32 blocks ----
        ((f32x4*)ssq)[(size_t)(bid - 512) * 256 + tid] = f32x4{0.f, 0.f, 0.f, 0.f};
    } else {
        // ---- cvt_bf16: h fp32 -> bf16, 8 elems/thread ----
        const int i = (bid - 544) * 256 + tid;
        if (i >= 4194304) return;
        const f32x4* xp = (const f32x4*)h + (size_t)i * 2;
        f32x4 a = xp[0], c = xp[1];
        u16x8 o;
        o[0]=f2bf(a[0]); o[1]=f2bf(a[1]); o[2]=f2bf(a[2]); o[3]=f2bf(a[3]);
        o[4]=f2bf(c[0]); o[5]=f2bf(c[1]); o[6]=f2bf(c[2]); o[7]=f2bf(c[3]);
        ((u16x8*)hbf)[i] = o;
    }
}

// ---------- GEMM: 256x256 tile, BK=64, 8-phase (T2+T3+T4+T5) ----------
// C[M,N] = A[M,K] * Bt[N,K]^T, bf16 in, fp32 acc.  (round-3 verified body,
// 880 TF @ K=1024 = plain-HIP template ceiling for this shape, m248v2.)
// 4 barriers/K-tile; counted vmcnt(6) per tile; tail tiles drain vmcnt(0).
// Stage schedule per tile T: p0:(T+1).A1  p1:(T+2).A0  p2:(T+2).B0
// p3:(T+2).B1 + vmcnt(6) (retires all of tile T+1; 6 = 3 half-tiles left).
// LDS swizzle (both-sides, rule #21): linear dest for global_load_lds, global
// SOURCE chunk pre-permuted chunk^=row&7, reads XOR byte^=((row&7)<<4).
// Grid 512 = 128 m-tiles x 4 n-tiles; xcd=id&7, all 4 n-tiles of an m-tile
// on one XCD (A panel L2-resident; 512%8==0 bijective).

#define STAGE(GB, SLOT) \
    gload16((GB) + g0, (char*)(SLOT) + d0); \
    gload16((GB) + g1, (char*)(SLOT) + d1);

#define READ_A(SLOT) \
    _Pragma("unroll") for (int f = 0; f < 4; ++f) \
    _Pragma("unroll") for (int kk = 0; kk < 2; ++kk) \
        a[f][kk] = *(const bf16x8*)((const char*)(SLOT) + \
            (((rhA + f * 32) << 7) + (cA ^ (kk << 6))));

#define READ_B(SLOT, GB) \
    _Pragma("unroll") for (int g = 0; g < 2; ++g) \
    _Pragma("unroll") for (int kk = 0; kk < 2; ++kk) \
        b[(GB) + g][kk] = *(const bf16x8*)((const char*)(SLOT) + \
            (((rhB + g * 64) << 7) + (cB ^ (kk << 6))));

#define MFMA_QUAD(FB, GB) \
    __builtin_amdgcn_s_setprio(1); \
    _Pragma("unroll") for (int f = 0; f < 4; ++f) \
    _Pragma("unroll") for (int g = 0; g < 2; ++g) \
    _Pragma("unroll") for (int kk = 0; kk < 2; ++kk) \
        acc[(FB) + f][(GB) + g] = __builtin_amdgcn_mfma_f32_16x16x32_bf16( \
            a[f][kk], b[(GB) + g][kk], acc[(FB) + f][(GB) + g], 0, 0, 0); \
    __builtin_amdgcn_s_setprio(0);

#define TILE_BODY(T, BB, VMW) { \
    bf16x8 a[4][2], b[4][2]; \
    /* p0: reads a0,b01(T); stage (T+1).A1 (slot's old a1(T-1) read done   */ \
    /* before T-1.p2's barrier).                                           */ \
    READ_A(lds[BB][0]); \
    READ_B(lds[BB][2], 0); \
    if ((T) + 1 < NT) { STAGE(A1p + ((T) + 1) * 64, lds[(BB) ^ 1][1]); } \
    MFMA_QUAD(0, 0); \
    S_BARRIER(); \
    /* p1: reads b23(T); stage (T+2).A0 over a0(T) (reads done < p0 bar). */ \
    READ_B(lds[BB][3], 2); \
    if ((T) + 2 < NT) { STAGE(A0p + ((T) + 2) * 64, lds[BB][0]); } \
    MFMA_QUAD(0, 2); \
    S_BARRIER(); \
    /* p2: reads a1(T); stage (T+2).B0 over b01(T) (reads done < p0 bar). */ \
    READ_A(lds[BB][1]); \
    if ((T) + 2 < NT) { STAGE(B0p + ((T) + 2) * 64, lds[BB][2]); } \
    MFMA_QUAD(4, 0); \
    S_BARRIER(); \
    /* p3: stage (T+2).B1 over b23(T) (reads done < p1 bar); counted vmcnt */ \
    /* publishes tile T+1 for next p0.                                     */ \
    if ((T) + 2 < NT) { STAGE(B1p + ((T) + 2) * 64, lds[BB][3]); } \
    MFMA_QUAD(4, 2); \
    asm volatile(VMW ::: "memory"); \
    S_BARRIER(); \
}

template <int ACC_SSQ, int HAS_SCALE, typename CT>
__global__ __launch_bounds__(512) void gemm256_8ph(const u16* __restrict__ A,
                                                   const u16* __restrict__ Bt,
                                                   CT* __restrict__ C,
                                                   float* __restrict__ ssq,
                                                   int M, int N, int K,
                                                   long long bt_batch_stride,
                                                   int rpb_log2) {
    __shared__ u16 lds[2][4][8192];   // 128 KiB
    const int tid  = threadIdx.x;
    const int lane = tid & 63;
    const int w    = tid >> 6;
    const int wm   = w >> 2;          // 0..1
    const int wn   = w & 3;           // 0..3

    // XCD-aware swizzle: 4 n-tiles of an m-tile share one XCD's L2.
    const int id  = blockIdx.x;
    const int xcd = id & 7;
    const int loc = id >> 3;
    const int mpx = (M >> 8) >> 3;            // m-tiles per XCD (16)
    const int mt  = xcd * mpx + (loc >> 2);
    const int ntt = loc & 3;
    const int m0  = mt << 8;
    const int n0  = ntt << 8;

    const u16* Btb = Bt + (size_t)(m0 >> rpb_log2) * (size_t)bt_batch_stride;
    const u16* A0p = A   + (size_t)m0 * K;
    const u16* A1p = A0p + (size_t)128 * K;
    const u16* B0p = Btb + (size_t)n0 * K;
    const u16* B1p = B0p + (size_t)128 * K;

    // staging: thread t loads rows (t>>3) and 64+(t>>3); source chunk
    // pre-swizzled so linear LDS + swizzled read is consistent (involution).
    const int    trow   = tid >> 3;
    const int    tchunk = (tid & 7) ^ (trow & 7);
    const size_t g0 = (size_t)trow * K + (size_t)tchunk * 8;   // u16 elems
    const size_t g1 = g0 + (size_t)64 * K;
    const int    d0 = tid * 16;                                 // bytes
    const int    d1 = d0 + 8192;

    const int NT = K >> 6;    // K-tiles (16); NT even, NT >= 4 assumed

    // per-lane LDS read bases (swizzle XOR constant per lane)
    const int rm  = lane & 15;
    const int kqb = (lane >> 4) << 4;                // byte offset of kq
    const int rhA = wm * 16 + rm;
    const int cA  = kqb ^ ((rhA & 7) << 4);
    const int rhB = wn * 16 + rm;
    const int cB  = kqb ^ ((rhB & 7) << 4);

    f32x4 acc[8][4] = {};

    // ---- prologue: stage T0 fully + T1.{A0,B0,B1}; vmcnt(6) -> T0 landed ----
    STAGE(A0p + 0,  lds[0][0]);
    STAGE(B0p + 0,  lds[0][2]);
    STAGE(B1p + 0,  lds[0][3]);
    STAGE(A1p + 0,  lds[0][1]);
    STAGE(A0p + 64, lds[1][0]);
    STAGE(B0p + 64, lds[1][2]);
    STAGE(B1p + 64, lds[1][3]);
    asm volatile("s_waitcnt vmcnt(6)" ::: "memory");
    S_BARRIER();

    #pragma unroll 1
    for (int T = 0; T < NT - 2; T += 2) {
        TILE_BODY(T, 0, "s_waitcnt vmcnt(6)");
        TILE_BODY(T + 1, 1, "s_waitcnt vmcnt(6)");
    }
    // tail: vmcnt(6) at NT-2.p3 would only prove A0(NT-1) landed; drain fully.
    TILE_BODY(NT - 2, 0, "s_waitcnt vmcnt(0)");
    TILE_BODY(NT - 1, 1, "s_waitcnt vmcnt(0)");

    // ---- epilogue ----  C/D: col=lane&15, row=(lane>>4)*4+reg [m89]
    __syncthreads();
    float* lred = (float*)&lds[0][0][0];   // 256 floats, LDS reuse
    if constexpr (HAS_SCALE) {
        if (tid < 256) {
            float q = ssq[m0 + tid];
            lred[tid] = 1.0f / fmaxf(sqrtf(q), 1e-12f);
        }
        __syncthreads();
    }
    if constexpr (ACC_SSQ) {
        if (tid < 256) lred[tid] = 0.f;
        __syncthreads();
    }
    const int cn = lane & 15;
    const int rq = (lane >> 4) * 4;
    #pragma unroll
    for (int f = 0; f < 8; ++f) {
        const int rbase = f * 32 + wm * 16 + rq;
        #pragma unroll
        for (int r = 0; r < 4; ++r) {
            const size_t rowoff = (size_t)(m0 + rbase + r) * N;
            float s = 0.f;
            #pragma unroll
            for (int g = 0; g < 4; ++g) {
                float x = acc[f][g][r];
                if constexpr (HAS_SCALE) x *= lred[rbase + r];
                if constexpr (ACC_SSQ) s += x * x;
                const int col = n0 + g * 64 + wn * 16 + cn;
                if constexpr (sizeof(CT) == 2) ((u16*)C)[rowoff + col] = f2bf(x);
                else                           C[rowoff + col] = x;
            }
            if constexpr (ACC_SSQ) {
                s += __shfl_xor(s, 1);
                s += __shfl_xor(s, 2);
                s += __shfl_xor(s, 4);
                s += __shfl_xor(s, 8);
                if (cn == 0) atomicAdd(&lred[rbase + r], s);  // 4 wn-waves/row
            }
        }
    }
    if constexpr (ACC_SSQ) {
        __syncthreads();
        if (tid < 256) atomicAdd(&ssq[m0 + tid], lred[tid]);  // 4 n-blocks/row
    }
}

// ---------- launch ----------
// B=4, S=8192, HID=PROJ=1024, NH=16, HD=64; M = B*S = 32768
// ws usage: 77.7 MiB. hbf lives in d_out's first half (dead after gemm1;
// gemm2 overwrites all of d_out — stream-ordered, safe).
extern "C" void kernel_launch(void* const* d_in, const int* in_sizes, int n_in,
                              void* d_out, int out_size, void* d_ws, size_t ws_size,
                              hipStream_t stream) {
    const float* h  = (const float*)d_in[0];   // [4,8192,1024]
    const float* Wq = (const float*)d_in[1];   // [1024,1024]
    const float* Wo = (const float*)d_in[7];   // [1024,1024]
    const float* M0 = (const float*)d_in[8];   // [4,16,64,64]
    float* out = (float*)d_out;

    char* ws = (char*)d_ws;
    u16*   hbf  = (u16*)d_out;                 // 67,108,864 B (first half of out)
    u16*   P    = (u16*)(ws);                  // 67,108,864 B
    u16*   WqT  = (u16*)(ws + 67108864);       //  2,097,152 B
    u16*   W2T  = (u16*)(ws + 69206016);       //  8,388,608 B
    float* ssq  = (float*)(ws + 77594624);     //    131,072 B  (end: 77,725,696)

    const int M = 32768, N = 1024, K = 1024;

    // one fused prep dispatch: w2t(256) | transpose(256) | ssq-zero(32) | cvt(16384)
    prep<<<16928, 256, 0, stream>>>(h, hbf, Wq, WqT, M0, Wo, W2T, ssq);
    // P = h @ Wq (bf16, un-normalized) + per-row ssq via atomics
    gemm256_8ph<1, 0, u16><<<512, 512, 0, stream>>>(
        hbf, WqT, P, ssq, M, N, K, 0, 0);
    // out = (1/max(sqrt(ssq),1e-12))[m] * (P @ W2T[batch]) ; batch = m >> 13
    gemm256_8ph<0, 1, float><<<512, 512, 0, stream>>>(
        P, W2T, out, ssq, M, N, K, (long long)1024 * 1024, 13);
}